// Round 7
// baseline (179.413 us; speedup 1.0000x reference)
//
#include <hip/hip_runtime.h>

#define IN_DIM 2048
#define OUT_DIM 2048
#define EPS 1e-8f

#define BK 128                 // i8 bytes per K-tile
#define NKT (IN_DIM / BK)      // 16 K-tiles
#define HALF 16384             // A half-tile: 256 rows x 64 B (granule-major)
// LDS map (65536 B, A only): ks0 @ {0,16K} (dbuf) | ks1 @ {32K,48K} (dbuf)

using int32x4 = __attribute__((ext_vector_type(4))) int;

// ---------------- Kernel 1: fused quantx (blocks 0..4095) + absum (blocks 4096..5119) ----
__global__ __launch_bounds__(256) void prep_kernel(const float* __restrict__ x,
                                                   signed char* __restrict__ xq,
                                                   float* __restrict__ beta_arr,
                                                   int tokens,
                                                   const float* __restrict__ w,
                                                   double* __restrict__ sum, int n4) {
    if (blockIdx.x < 4096) {
        // ---- per-token beta + quantize x: one 64-lane wave per token ----
        const int lane = threadIdx.x & 63;
        const int wave = threadIdx.x >> 6;
        const int t = blockIdx.x * 4 + wave;
        if (t >= tokens) return;
        const float4* row = (const float4*)(x + (size_t)t * IN_DIM);
        float4 v[8];
        float m = 0.f;
#pragma unroll
        for (int j = 0; j < 8; ++j) {
            v[j] = row[lane + 64 * j];
            m = fmaxf(m, fmaxf(fmaxf(fabsf(v[j].x), fabsf(v[j].y)),
                               fmaxf(fabsf(v[j].z), fabsf(v[j].w))));
        }
#pragma unroll
        for (int off = 32; off; off >>= 1) m = fmaxf(m, __shfl_xor(m, off));
        const float beta = fmaxf(m * (1.f / 127.f), EPS);
        if (lane == 0) beta_arr[t] = beta;
        char4* orow = (char4*)(xq + (size_t)t * IN_DIM);
#pragma unroll
        for (int j = 0; j < 8; ++j) {
            char4 q;
            q.x = (signed char)fminf(fmaxf(rintf(v[j].x / beta), -127.f), 127.f);
            q.y = (signed char)fminf(fmaxf(rintf(v[j].y / beta), -127.f), 127.f);
            q.z = (signed char)fminf(fmaxf(rintf(v[j].z / beta), -127.f), 127.f);
            q.w = (signed char)fminf(fmaxf(rintf(v[j].w / beta), -127.f), 127.f);
            orow[lane + 64 * j] = q;
        }
    } else {
        // ---- sum of |W| ----
        int tid = (blockIdx.x - 4096) * blockDim.x + threadIdx.x;
        int stride = 1024 * blockDim.x;
        float s = 0.f;
        for (int i = tid; i < n4; i += stride) {
            float4 vv = ((const float4*)w)[i];
            s += fabsf(vv.x) + fabsf(vv.y) + fabsf(vv.z) + fabsf(vv.w);
        }
        for (int off = 32; off; off >>= 1) s += __shfl_down(s, off);
        __shared__ float wsum[4];
        int lane = threadIdx.x & 63, wave = threadIdx.x >> 6;
        if (lane == 0) wsum[wave] = s;
        __syncthreads();
        if (threadIdx.x == 0) {
            double tt = (double)wsum[0] + (double)wsum[1] + (double)wsum[2] + (double)wsum[3];
            atomicAdd(sum, tt);
        }
    }
}

// ---------------- Kernel 2: quantize W to ternary int8 ----------------
__global__ __launch_bounds__(256) void quantw_kernel(const float* __restrict__ w,
                                                     const double* __restrict__ sumptr,
                                                     signed char* __restrict__ wq,
                                                     float* __restrict__ alpha_out, int n4) {
    float alpha = fmaxf((float)(*sumptr * (1.0 / (double)(IN_DIM * OUT_DIM))), EPS);
    int i = blockIdx.x * blockDim.x + threadIdx.x;
    if (i == 0) *alpha_out = alpha;
    if (i >= n4) return;
    float4 v = ((const float4*)w)[i];
    char4 q;
    q.x = (signed char)fminf(fmaxf(rintf(v.x / alpha), -1.f), 1.f);
    q.y = (signed char)fminf(fmaxf(rintf(v.y / alpha), -1.f), 1.f);
    q.z = (signed char)fminf(fmaxf(rintf(v.z / alpha), -1.f), 1.f);
    q.w = (signed char)fminf(fmaxf(rintf(v.w / alpha), -1.f), 1.f);
    ((char4*)wq)[i] = q;
}

// ---------------- GEMM helpers ----------------
__device__ __forceinline__ void gll(const signed char* g, signed char* l) {
    __builtin_amdgcn_global_load_lds((const __attribute__((address_space(1))) void*)g,
        (__attribute__((address_space(3))) void*)l, 16, 0, 0);
}

// 32 MFMAs: full half-tile, B operand from registers (named buffer)
#define MFMA32(B)                                                                              \
    __builtin_amdgcn_s_setprio(1);                                                             \
    _Pragma("unroll")                                                                          \
    for (int m_ = 0; m_ < 8; ++m_)                                                             \
        _Pragma("unroll")                                                                      \
        for (int n_ = 0; n_ < 4; ++n_)                                                         \
            acc[m_][n_] = __builtin_amdgcn_mfma_i32_16x16x64_i8(                               \
                af[m_], B[n_], acc[m_][n_], 0, 0, 0);                                          \
    __builtin_amdgcn_s_setprio(0);

// One K-tile, B direct global->VGPR (wq is L2-resident: 4 MiB), A staged via gll.
// Per half: 8 A ds_reads + 4 B global loads (next half) + 2 A-glls (tile T+1) +
// vmcnt(6) pre-MFMA + barrier post-MFMA. The vmcnt(6) leaves this half's 6 VMEM
// in flight and drains the previous half's 6 -> every consumed buffer (B regs,
// A-gll LDS) has one full half-tile (~1300 cyc) of landing slack. Never vmcnt(0)
// in steady state. bA/bB are NAMED ping-pong buffers (static indexing only).
template<bool STG, bool TAIL>
__device__ __forceinline__ void ktile(int T, signed char* lds, int32x4 (&acc)[8][4],
                                      int32x4 (&bA)[4], int32x4 (&bB)[4],
                                      const signed char* const (&bAddr)[4],
                                      int aoff, int f0, int f1,
                                      const signed char* a0, const signed char* a1) {
    const int s = (T & 1) * HALF;
    const int d = ((T + 1) & 1) * HALF;
    const int ko = T * BK;             // imm-foldable (max 1984 < 4096)
    const int kn = (T + 1) * BK;
    int32x4 af[8];

    // ---- half ks0: consume bA = B(T,ks0) ----
#pragma unroll
    for (int m = 0; m < 8; ++m) af[m] = *(const int32x4*)(lds + s + aoff + m * 1024);
#pragma unroll
    for (int n = 0; n < 4; ++n) bB[n] = *(const int32x4*)(bAddr[n] + ko + 64);   // B(T,ks1)
    if constexpr (STG) { gll(a0 + kn, lds + d + f0); gll(a1 + kn, lds + d + f1); } // A(T+1,ks0)
    if constexpr (TAIL) asm volatile("s_waitcnt vmcnt(4)" ::: "memory");  // drain bA + A(T,ks1) glls
    else                asm volatile("s_waitcnt vmcnt(6)" ::: "memory");  // drain prev half's 6
    MFMA32(bA)
    __builtin_amdgcn_s_barrier();

    // ---- half ks1: consume bB = B(T,ks1) ----
#pragma unroll
    for (int m = 0; m < 8; ++m) af[m] = *(const int32x4*)(lds + 32768 + s + aoff + m * 1024);
    if constexpr (!TAIL) {
#pragma unroll
        for (int n = 0; n < 4; ++n) bA[n] = *(const int32x4*)(bAddr[n] + kn);    // B(T+1,ks0)
        if constexpr (STG) { gll(a0 + kn + 64, lds + 32768 + d + f0);
                             gll(a1 + kn + 64, lds + 32768 + d + f1); }          // A(T+1,ks1)
        asm volatile("s_waitcnt vmcnt(6)" ::: "memory");   // drain half0's 6 (bB + A(T+1,ks0))
    } else {
        asm volatile("s_waitcnt vmcnt(0)" ::: "memory");   // final drain (bB)
    }
    MFMA32(bB)
    if constexpr (!TAIL) __builtin_amdgcn_s_barrier();
}

// ---------------- Kernel 3: int8 MFMA GEMM, 256x256 tile, B-from-registers ----------------
// 512 threads = 8 waves (2M x 4N); wave-tile 128x64; acc[8][4] (128 VGPR) + af 32 +
// bA/bB 32 + addrs ~15 -> ~210 regs, 2 waves/SIMD. LDS 64 KiB = A only, granule-major
// (0 bank conflicts), dbuf-2 slots. Per half the LDS-read convoy is 8 reads (was 12)
// and gll traffic is halved; B granules (1 KiB lane-contiguous, 16 full 64B lines per
// load) stream from the L2-resident 4 MiB wq.
__global__ __launch_bounds__(512, 2) void gemm_kernel(const signed char* __restrict__ xq,
                                                      const signed char* __restrict__ wq,
                                                      const float* __restrict__ beta,
                                                      const float* __restrict__ alpha_p,
                                                      float* __restrict__ out) {
    extern __shared__ signed char lds[];   // 65536
    const int tid = threadIdx.x;
    const int lane = tid & 63;
    const int wave = tid >> 6;
    const int wm = wave >> 2;              // 0..1
    const int wn = wave & 3;               // 0..3
    const int row0 = blockIdx.x * 256;
    const int col0 = blockIdx.y * 256;

    // A staging: 2 x 16B chunks per half-tile per thread (granule-major:
    // addr = g*1024 + kg*256 + r*16; row = g*16+r, kg = 16B k-group)
    const int f0 = tid * 16;
    const int f1 = f0 + 8192;
    const int g0 = f0 >> 10, kg0 = (f0 >> 8) & 3, r0 = (f0 >> 4) & 15;
    const int g1 = f1 >> 10, kg1 = (f1 >> 8) & 3, r1 = (f1 >> 4) & 15;
    const signed char* a0 = xq + (size_t)(row0 + g0 * 16 + r0) * IN_DIM + kg0 * 16;
    const signed char* a1 = xq + (size_t)(row0 + g1 * 16 + r1) * IN_DIM + kg1 * 16;

    // B fragment addresses (per-lane, same element map the ds_read had):
    // row = col0 + wn*64 + n*16 + (lane&15), k = T*128 + ks*64 + (lane>>4)*16
    const signed char* bAddr[4];
#pragma unroll
    for (int n = 0; n < 4; ++n)
        bAddr[n] = wq + (size_t)(col0 + wn * 64 + n * 16 + (lane & 15)) * IN_DIM
                      + ((lane >> 4) << 4);

    const int kr = (lane >> 4) * 256 + (lane & 15) * 16;
    const int aoff = wm * 8192 + kr;       // + mi*1024, mi<8

    int32x4 acc[8][4] = {};
    int32x4 bA[4], bB[4];

    // prologue: stage A(0) both halves into slot 0; load B(0,ks0)
    gll(a0, lds + f0);           gll(a1, lds + f1);                // A(0,ks0)
    gll(a0 + 64, lds + 32768 + f0); gll(a1 + 64, lds + 32768 + f1); // A(0,ks1)
#pragma unroll
    for (int n = 0; n < 4; ++n) bA[n] = *(const int32x4*)(bAddr[n]);
    asm volatile("s_waitcnt vmcnt(0)" ::: "memory");
    __builtin_amdgcn_s_barrier();

    for (int T = 0; T < NKT - 1; ++T)
        ktile<true, false>(T, lds, acc, bA, bB, bAddr, aoff, f0, f1, a0, a1);
    ktile<false, true>(NKT - 1, lds, acc, bA, bB, bAddr, aoff, f0, f1, a0, a1);

    // epilogue: dequant + store (C layout: col=lane&15, row=(lane>>4)*4+reg)
    const float alpha = *alpha_p;
#pragma unroll
    for (int mi = 0; mi < 8; ++mi) {
        int rbase = row0 + wm * 128 + mi * 16 + ((lane >> 4) << 2);
#pragma unroll
        for (int r = 0; r < 4; ++r) {
            int row = rbase + r;
            float scale = alpha * beta[row];
#pragma unroll
            for (int n = 0; n < 4; ++n) {
                int col = col0 + wn * 64 + n * 16 + (lane & 15);
                out[(size_t)row * OUT_DIM + col] = (float)acc[mi][n][r] * scale;
            }
        }
    }
}

extern "C" void kernel_launch(void* const* d_in, const int* in_sizes, int n_in,
                              void* d_out, int out_size, void* d_ws, size_t ws_size,
                              hipStream_t stream) {
    const float* x = (const float*)d_in[0];
    const float* w = (const float*)d_in[1];
    float* out = (float*)d_out;

    const int tokens = in_sizes[0] / IN_DIM;          // 16384
    const int n_w = in_sizes[1];                      // 4194304
    const int n_w4 = n_w / 4;

    char* ws = (char*)d_ws;
    double* d_sum = (double*)ws;                      // 8 B
    float* d_alpha = (float*)(ws + 8);                // 4 B
    float* d_beta = (float*)(ws + 256);               // tokens * 4 B
    signed char* d_wq = (signed char*)(ws + 256 + 65536);
    signed char* d_xq = d_wq + (size_t)n_w;

    hipMemsetAsync(d_ws, 0, 16, stream);

    // prep: quantx (4096 blocks) + absum (1024 blocks) fused
    prep_kernel<<<5120, 256, 0, stream>>>(x, d_xq, d_beta, tokens, w, d_sum, n_w4);
    quantw_kernel<<<(n_w4 + 255) / 256, 256, 0, stream>>>(w, d_sum, d_wq, d_alpha, n_w4);

    hipFuncSetAttribute((const void*)gemm_kernel,
                        hipFuncAttributeMaxDynamicSharedMemorySize, 65536);

    dim3 grid(16384 / 256, OUT_DIM / 256);            // (64, 8) row-fastest
    gemm_kernel<<<grid, 512, 65536, stream>>>(d_xq, d_wq, d_beta, d_alpha, out);
}

// Round 8
// 138.623 us; speedup vs baseline: 1.2943x; 1.2943x over previous
//
#include <hip/hip_runtime.h>

#define IN_DIM 2048
#define OUT_DIM 2048
#define EPS 1e-8f

#define BK 128                 // i8 bytes per K-tile
#define NKT (IN_DIM / BK)      // 16 K-tiles
#define HALF 16384             // half-tile: 256 rows x 64 B (granule-major)
// LDS map (131072 B): A ks0 @ 0,16K | A ks1 @ 32K,48K | B ks0 @ 64K,80K | B ks1 @ 96K,112K

using int32x4 = __attribute__((ext_vector_type(4))) int;

// ---------------- Kernel 1: fused quantx (blocks 0..4095) + absum (blocks 4096..5119) ----
__global__ __launch_bounds__(256) void prep_kernel(const float* __restrict__ x,
                                                   signed char* __restrict__ xq,
                                                   float* __restrict__ beta_arr,
                                                   int tokens,
                                                   const float* __restrict__ w,
                                                   double* __restrict__ sum, int n4) {
    if (blockIdx.x < 4096) {
        // ---- per-token beta + quantize x: one 64-lane wave per token ----
        const int lane = threadIdx.x & 63;
        const int wave = threadIdx.x >> 6;
        const int t = blockIdx.x * 4 + wave;
        if (t >= tokens) return;
        const float4* row = (const float4*)(x + (size_t)t * IN_DIM);
        float4 v[8];
        float m = 0.f;
#pragma unroll
        for (int j = 0; j < 8; ++j) {
            v[j] = row[lane + 64 * j];
            m = fmaxf(m, fmaxf(fmaxf(fabsf(v[j].x), fabsf(v[j].y)),
                               fmaxf(fabsf(v[j].z), fabsf(v[j].w))));
        }
#pragma unroll
        for (int off = 32; off; off >>= 1) m = fmaxf(m, __shfl_xor(m, off));
        const float beta = fmaxf(m * (1.f / 127.f), EPS);
        if (lane == 0) beta_arr[t] = beta;
        char4* orow = (char4*)(xq + (size_t)t * IN_DIM);
#pragma unroll
        for (int j = 0; j < 8; ++j) {
            char4 q;
            q.x = (signed char)fminf(fmaxf(rintf(v[j].x / beta), -127.f), 127.f);
            q.y = (signed char)fminf(fmaxf(rintf(v[j].y / beta), -127.f), 127.f);
            q.z = (signed char)fminf(fmaxf(rintf(v[j].z / beta), -127.f), 127.f);
            q.w = (signed char)fminf(fmaxf(rintf(v[j].w / beta), -127.f), 127.f);
            orow[lane + 64 * j] = q;
        }
    } else {
        // ---- sum of |W| ----
        int tid = (blockIdx.x - 4096) * blockDim.x + threadIdx.x;
        int stride = 1024 * blockDim.x;
        float s = 0.f;
        for (int i = tid; i < n4; i += stride) {
            float4 vv = ((const float4*)w)[i];
            s += fabsf(vv.x) + fabsf(vv.y) + fabsf(vv.z) + fabsf(vv.w);
        }
        for (int off = 32; off; off >>= 1) s += __shfl_down(s, off);
        __shared__ float wsum[4];
        int lane = threadIdx.x & 63, wave = threadIdx.x >> 6;
        if (lane == 0) wsum[wave] = s;
        __syncthreads();
        if (threadIdx.x == 0) {
            double tt = (double)wsum[0] + (double)wsum[1] + (double)wsum[2] + (double)wsum[3];
            atomicAdd(sum, tt);
        }
    }
}

// ---------------- Kernel 2: quantize W to ternary int8 ----------------
__global__ __launch_bounds__(256) void quantw_kernel(const float* __restrict__ w,
                                                     const double* __restrict__ sumptr,
                                                     signed char* __restrict__ wq,
                                                     float* __restrict__ alpha_out, int n4) {
    float alpha = fmaxf((float)(*sumptr * (1.0 / (double)(IN_DIM * OUT_DIM))), EPS);
    int i = blockIdx.x * blockDim.x + threadIdx.x;
    if (i == 0) *alpha_out = alpha;
    if (i >= n4) return;
    float4 v = ((const float4*)w)[i];
    char4 q;
    q.x = (signed char)fminf(fmaxf(rintf(v.x / alpha), -1.f), 1.f);
    q.y = (signed char)fminf(fmaxf(rintf(v.y / alpha), -1.f), 1.f);
    q.z = (signed char)fminf(fmaxf(rintf(v.z / alpha), -1.f), 1.f);
    q.w = (signed char)fminf(fmaxf(rintf(v.w / alpha), -1.f), 1.f);
    ((char4*)wq)[i] = q;
}

// ---------------- GEMM helpers ----------------
__device__ __forceinline__ void gll(const signed char* g, signed char* l) {
    __builtin_amdgcn_global_load_lds((const __attribute__((address_space(1))) void*)g,
        (__attribute__((address_space(3))) void*)l, 16, 0, 0);
}

#define CLUSTER(BASE, AF)                                                                      \
    __builtin_amdgcn_s_setprio(1);                                                             \
    _Pragma("unroll")                                                                          \
    for (int m_ = 0; m_ < 4; ++m_)                                                             \
        _Pragma("unroll")                                                                      \
        for (int n_ = 0; n_ < 4; ++n_)                                                         \
            acc[(BASE) + m_][n_] = __builtin_amdgcn_mfma_i32_16x16x64_i8(                      \
                AF[m_], bf[n_], acc[(BASE) + m_][n_], 0, 0, 0);                                \
    __builtin_amdgcn_s_setprio(0);

// One K-tile, NO lgkm drains (compiler emits counted lgkm at MFMA use sites so
// trailing reads drain under MFMA execution). Structure:
//   R1(8 reads) G1 R2(4 reads) C1 G2 C2 [vmcnt(4); barrier]   <- Ah1/Bh1(T) landed
//   R3(8 reads) G3 R4(4 reads) C3 G4 C4 [vmcnt(4); barrier]   <- Ah0/Bh0(T+1) landed
// Stage order per tile: G1=Ah0(T+1) G2=Bh0(T+1) G3=Ah1(T+1) G4=Bh1(T+1) (2 gll each).
// Per-wave vmcnt(4)+barrier gate => all waves' older gll landed (cross-wave safe).
// Never vmcnt(0) in main loop; tail drains.  [best-measured GEMM: 90.2-91.6 us]
template<bool STG, bool TAIL>
__device__ __forceinline__ void ktile(int T, signed char* lds, int32x4 (&acc)[8][4],
                                      int aoff, int boff, int f0, int f1,
                                      const signed char* a0, const signed char* a1,
                                      const signed char* b0, const signed char* b1) {
    const int s = (T & 1) * HALF;
    const int d = ((T + 1) & 1) * HALF;
    const size_t ko = (size_t)(T + 1) * BK;
    int32x4 af0[4], af1[4], bf[4];

    // ---- half ks0 ----
#pragma unroll
    for (int m = 0; m < 4; ++m) af0[m] = *(const int32x4*)(lds + s + aoff + m * 1024);
#pragma unroll
    for (int n = 0; n < 4; ++n) bf[n] = *(const int32x4*)(lds + 65536 + s + boff + n * 1024);
    if constexpr (STG) { gll(a0 + ko, lds + d + f0); gll(a1 + ko, lds + d + f1); }
#pragma unroll
    for (int m = 0; m < 4; ++m) af1[m] = *(const int32x4*)(lds + s + aoff + 4096 + m * 1024);
    CLUSTER(0, af0)
    if constexpr (STG) { gll(b0 + ko, lds + 65536 + d + f0); gll(b1 + ko, lds + 65536 + d + f1); }
    CLUSTER(4, af1)
    if constexpr (TAIL) asm volatile("s_waitcnt vmcnt(0)" ::: "memory");
    else                asm volatile("s_waitcnt vmcnt(4)" ::: "memory");
    __builtin_amdgcn_s_barrier();

    // ---- half ks1 ----
#pragma unroll
    for (int m = 0; m < 4; ++m) af0[m] = *(const int32x4*)(lds + 32768 + s + aoff + m * 1024);
#pragma unroll
    for (int n = 0; n < 4; ++n) bf[n] = *(const int32x4*)(lds + 98304 + s + boff + n * 1024);
    if constexpr (STG) { gll(a0 + ko + 64, lds + 32768 + d + f0); gll(a1 + ko + 64, lds + 32768 + d + f1); }
#pragma unroll
    for (int m = 0; m < 4; ++m) af1[m] = *(const int32x4*)(lds + 32768 + s + aoff + 4096 + m * 1024);
    CLUSTER(0, af0)
    if constexpr (STG) { gll(b0 + ko + 64, lds + 98304 + d + f0); gll(b1 + ko + 64, lds + 98304 + d + f1); }
    CLUSTER(4, af1)
    if constexpr (!TAIL) {
        asm volatile("s_waitcnt vmcnt(4)" ::: "memory");
        __builtin_amdgcn_s_barrier();
    }
}

// ---------------- Kernel 3: int8 MFMA GEMM, 256x256 tile ----------------
// 512 threads = 8 waves (2M x 4N); wave-tile 128x64; acc[8][4] (128 AGPR).
// Granule-major half-tiles (0 bank conflicts), dbuf-2 slots, counted vmcnt(4),
// compiler-counted lgkm (no drains), 2 barriers per K-tile.
__global__ __launch_bounds__(512, 2) void gemm_kernel(const signed char* __restrict__ xq,
                                                      const signed char* __restrict__ wq,
                                                      const float* __restrict__ beta,
                                                      const float* __restrict__ alpha_p,
                                                      float* __restrict__ out) {
    extern __shared__ signed char lds[];   // 131072
    const int tid = threadIdx.x;
    const int lane = tid & 63;
    const int wave = tid >> 6;
    const int wm = wave >> 2;              // 0..1
    const int wn = wave & 3;               // 0..3
    const int row0 = blockIdx.x * 256;
    const int col0 = blockIdx.y * 256;

    // staging: 2 x 16B chunks per half-tile per thread (granule-major:
    // addr = g*1024 + kg*256 + r*16; row = g*16+r, kg = 16B k-group)
    const int f0 = tid * 16;
    const int f1 = f0 + 8192;
    const int g0 = f0 >> 10, kg0 = (f0 >> 8) & 3, r0 = (f0 >> 4) & 15;
    const int g1 = f1 >> 10, kg1 = (f1 >> 8) & 3, r1 = (f1 >> 4) & 15;
    const signed char* a0 = xq + (size_t)(row0 + g0 * 16 + r0) * IN_DIM + kg0 * 16;
    const signed char* a1 = xq + (size_t)(row0 + g1 * 16 + r1) * IN_DIM + kg1 * 16;
    const signed char* b0 = wq + (size_t)(col0 + g0 * 16 + r0) * IN_DIM + kg0 * 16;
    const signed char* b1 = wq + (size_t)(col0 + g1 * 16 + r1) * IN_DIM + kg1 * 16;

    const int kr = (lane >> 4) * 256 + (lane & 15) * 16;
    const int aoff = wm * 8192 + kr;       // + mh*4096 + m*1024
    const int boff = wn * 4096 + kr;       // + n*1024

    int32x4 acc[8][4] = {};

    // prologue: tile 0's four half-tiles into slot 0 (consumption order)
    gll(a0, lds + f0);              gll(a1, lds + f1);               // Ah0
    gll(b0, lds + 65536 + f0);      gll(b1, lds + 65536 + f1);       // Bh0
    gll(a0 + 64, lds + 32768 + f0); gll(a1 + 64, lds + 32768 + f1);  // Ah1
    gll(b0 + 64, lds + 98304 + f0); gll(b1 + 64, lds + 98304 + f1);  // Bh1
    asm volatile("s_waitcnt vmcnt(4)" ::: "memory");                 // Ah0,Bh0 landed
    __builtin_amdgcn_s_barrier();

    for (int T = 0; T < NKT - 1; ++T)
        ktile<true, false>(T, lds, acc, aoff, boff, f0, f1, a0, a1, b0, b1);
    ktile<false, true>(NKT - 1, lds, acc, aoff, boff, f0, f1, a0, a1, b0, b1);

    // epilogue: dequant + store (C layout: col=lane&15, row=(lane>>4)*4+reg)
    const float alpha = *alpha_p;
#pragma unroll
    for (int mi = 0; mi < 8; ++mi) {
        int rbase = row0 + wm * 128 + mi * 16 + ((lane >> 4) << 2);
#pragma unroll
        for (int r = 0; r < 4; ++r) {
            int row = rbase + r;
            float scale = alpha * beta[row];
#pragma unroll
            for (int n = 0; n < 4; ++n) {
                int col = col0 + wn * 64 + n * 16 + (lane & 15);
                out[(size_t)row * OUT_DIM + col] = (float)acc[mi][n][r] * scale;
            }
        }
    }
}

extern "C" void kernel_launch(void* const* d_in, const int* in_sizes, int n_in,
                              void* d_out, int out_size, void* d_ws, size_t ws_size,
                              hipStream_t stream) {
    const float* x = (const float*)d_in[0];
    const float* w = (const float*)d_in[1];
    float* out = (float*)d_out;

    const int tokens = in_sizes[0] / IN_DIM;          // 16384
    const int n_w = in_sizes[1];                      // 4194304
    const int n_w4 = n_w / 4;

    char* ws = (char*)d_ws;
    double* d_sum = (double*)ws;                      // 8 B
    float* d_alpha = (float*)(ws + 8);                // 4 B
    float* d_beta = (float*)(ws + 256);               // tokens * 4 B
    signed char* d_wq = (signed char*)(ws + 256 + 65536);
    signed char* d_xq = d_wq + (size_t)n_w;

    hipMemsetAsync(d_ws, 0, 16, stream);

    // prep: quantx (4096 blocks, wave-per-token) + absum (1024 blocks) fused
    prep_kernel<<<5120, 256, 0, stream>>>(x, d_xq, d_beta, tokens, w, d_sum, n_w4);
    quantw_kernel<<<(n_w4 + 255) / 256, 256, 0, stream>>>(w, d_sum, d_wq, d_alpha, n_w4);

    hipFuncSetAttribute((const void*)gemm_kernel,
                        hipFuncAttributeMaxDynamicSharedMemorySize, 131072);

    dim3 grid(16384 / 256, OUT_DIM / 256);            // (64, 8) row-fastest
    gemm_kernel<<<grid, 512, 131072, stream>>>(d_xq, d_wq, d_beta, d_alpha, out);
}